// Round 15
// baseline (120.702 us; speedup 1.0000x reference)
//
#include <hip/hip_runtime.h>
#include <math.h>

#define B_  64
#define VL 256
#define TL 512
#define HD 512
#define KV 127   // (VL-1)/2
#define KT 255   // (TL-1)/2
#define EPSF 1e-8f

typedef __attribute__((ext_vector_type(8))) short short8;
typedef __attribute__((ext_vector_type(4))) float f32x4;

// workspace layout in 4-byte elements
#define WS_CNT   0                        // B_ u32 arrival counters (memset 0 each call)
#define WS_ROWP  (B_)                     // B_*2*VL u32 partial row maxes
#define WS_COLP  (WS_ROWP + B_*2*VL)      // B_*2*TL u32 partial col maxes
#define WS_SRC   (WS_COLP + B_*2*TL)      // B_*768 i32 gather sources

__device__ __forceinline__ unsigned fkey(float f) {
    unsigned u = __float_as_uint(f);
    return (u & 0x80000000u) ? ~u : (u | 0x80000000u);  // order-preserving float->uint
}

__device__ __forceinline__ unsigned cvt_pk_bf16(float a, float b) {
    unsigned r;
    asm("v_cvt_pk_bf16_f32 %0, %1, %2" : "=v"(r) : "v"(a), "v"(b));
    return r;   // {bf16(a) lo, bf16(b) hi}, RNE
}

// trunc-split one pair: hh = {a.hi16,b.hi16}, ll = {bf16(a-ah), bf16(b-bh)}
__device__ __forceinline__ void split_pair(float a, float b, unsigned& hh, unsigned& ll, float& ss) {
    ss = fmaf(a, a, ss);
    ss = fmaf(b, b, ss);
    unsigned ua = __float_as_uint(a) & 0xFFFF0000u;
    unsigned ub = __float_as_uint(b) & 0xFFFF0000u;
    hh = __builtin_amdgcn_perm(ub, ua, 0x07060302u);
    ll = cvt_pk_bf16(a - __uint_as_float(ua), b - __uint_as_float(ub));
}

// stage 8 f32 -> h/l planes (uint4 each)
__device__ __forceinline__ void cvt_store8(unsigned* __restrict__ ph, unsigned* __restrict__ pl,
                                           float4 x0, float4 x1, float& ss) {
    unsigned hh0, hh1, hh2, hh3, ll0, ll1, ll2, ll3;
    split_pair(x0.x, x0.y, hh0, ll0, ss);
    split_pair(x0.z, x0.w, hh1, ll1, ss);
    split_pair(x1.x, x1.y, hh2, ll2, ss);
    split_pair(x1.z, x1.w, hh3, ll3, ss);
    *(uint4*)ph = (uint4){hh0, hh1, hh2, hh3};
    *(uint4*)pl = (uint4){ll0, ll1, ll2, ll3};
}

__device__ __forceinline__ void ast(unsigned* p, unsigned v) {
    __hip_atomic_store(p, v, __ATOMIC_RELAXED, __HIP_MEMORY_SCOPE_AGENT);
}
__device__ __forceinline__ unsigned ald(const unsigned* p) {
    return __hip_atomic_load(p, __ATOMIC_RELAXED, __HIP_MEMORY_SCOPE_AGENT);
}

// per-batch 128x256 tile, K=512, 8 waves of 64x64: split-bf16 3-pass MFMA,
// dbuf LDS, chunk-XOR swizzle. Tail: LAST-arriving block per batch runs the
// ballot select inline (no spin-waiting anywhere); others exit.
__global__ __launch_bounds__(512, 1) void k_simmax(const float* __restrict__ video,
                                                   const float* __restrict__ text,
                                                   unsigned* __restrict__ cnt,
                                                   unsigned* __restrict__ rowp,
                                                   unsigned* __restrict__ colp,
                                                   unsigned* __restrict__ srcidx) {
    __shared__ __align__(16) unsigned pA[2][2][2048];   // [buf][h/l][128 rows x 16 uints]
    __shared__ __align__(16) unsigned pB[2][2][4096];   // [buf][h/l][256 rows x 16 uints]
    __shared__ float vns_s[128], tns_s[256];
    __shared__ unsigned rowm[128], colm[256];
    __shared__ __align__(16) unsigned rk[VL];
    __shared__ __align__(16) unsigned ck[TL];
    __shared__ int wsumv[4], wsumt[8];
    __shared__ int sh_last;

    int bb = blockIdx.x;
    // XCD grouping: a batch's 4 blocks share one XCD (hw xcd = blockIdx % 8)
    int z = bb & 7, w = bb >> 3;
    int b  = z * 8 + (w >> 2);
    int mt = (w >> 1) & 1, nt = w & 1;
    int m0 = mt * 128, n0 = nt * 256;

    const float* Vb = video + (size_t)b * VL * HD;
    const float* Tb = text  + (size_t)b * TL * HD;

    int tid = threadIdx.x;
    int l = tid & 63, wid = tid >> 6;
    int fr = l & 15, g = l >> 4;
    int wm = (wid >> 2) * 64, wn = (wid & 3) * 64;   // wave tile: 64 x 64

    // staging: thread handles one 8-float chunk of A and two of B
    int rA = tid >> 2, c = tid & 3;
    int rB0 = rA, rB1 = 128 + rA;
    unsigned wA  = rA  * 16 + (c ^ ((rA  >> 1) & 3)) * 4;
    unsigned wB0 = rB0 * 16 + (c ^ ((rB0 >> 1) & 3)) * 4;
    unsigned wB1 = rB1 * 16 + (c ^ ((rB1 >> 1) & 3)) * 4;
    const float* aptr  = Vb + (size_t)(m0 + rA)  * HD + c * 8;
    const float* bptr0 = Tb + (size_t)(n0 + rB0) * HD + c * 8;
    const float* bptr1 = Tb + (size_t)(n0 + rB1) * HD + c * 8;

    f32x4 acc[4][4];
#pragma unroll
    for (int i = 0; i < 4; ++i)
#pragma unroll
        for (int j = 0; j < 4; ++j) acc[i][j] = (f32x4){0.f, 0.f, 0.f, 0.f};

    float sa = 0.f, sb0 = 0.f, sb1 = 0.f;

    // prologue: stage step 0; prefetch step 1 raw
    float4 a0  = *(const float4*)(aptr),      a1  = *(const float4*)(aptr + 4);
    float4 b00 = *(const float4*)(bptr0),     b01 = *(const float4*)(bptr0 + 4);
    float4 b10 = *(const float4*)(bptr1),     b11 = *(const float4*)(bptr1 + 4);
    cvt_store8(&pA[0][0][wA],  &pA[0][1][wA],  a0,  a1,  sa);
    cvt_store8(&pB[0][0][wB0], &pB[0][1][wB0], b00, b01, sb0);
    cvt_store8(&pB[0][0][wB1], &pB[0][1][wB1], b10, b11, sb1);
    a0  = *(const float4*)(aptr + 32);  a1  = *(const float4*)(aptr + 36);
    b00 = *(const float4*)(bptr0 + 32); b01 = *(const float4*)(bptr0 + 36);
    b10 = *(const float4*)(bptr1 + 32); b11 = *(const float4*)(bptr1 + 36);
    __syncthreads();

    for (int t = 0; t < 16; ++t) {
        int cur = t & 1, nxt = cur ^ 1;
        short8 fah[4], fal[4], fbh[4], fbl[4];
#pragma unroll
        for (int i = 0; i < 4; ++i) {
            int row = wm + i * 16 + fr;
            unsigned ridx = row * 16 + (g ^ ((row >> 1) & 3)) * 4;
            fah[i] = *(const short8*)&pA[cur][0][ridx];
            fal[i] = *(const short8*)&pA[cur][1][ridx];
        }
#pragma unroll
        for (int j = 0; j < 4; ++j) {
            int row = wn + j * 16 + fr;
            unsigned ridx = row * 16 + (g ^ ((row >> 1) & 3)) * 4;
            fbh[j] = *(const short8*)&pB[cur][0][ridx];
            fbl[j] = *(const short8*)&pB[cur][1][ridx];
        }
        if (t < 15) {
            cvt_store8(&pA[nxt][0][wA],  &pA[nxt][1][wA],  a0,  a1,  sa);
            cvt_store8(&pB[nxt][0][wB0], &pB[nxt][1][wB0], b00, b01, sb0);
            cvt_store8(&pB[nxt][0][wB1], &pB[nxt][1][wB1], b10, b11, sb1);
            if (t < 14) {
                const float* ap  = aptr  + (t + 2) * 32;
                const float* bp0 = bptr0 + (t + 2) * 32;
                const float* bp1 = bptr1 + (t + 2) * 32;
                a0  = *(const float4*)ap;  a1  = *(const float4*)(ap + 4);
                b00 = *(const float4*)bp0; b01 = *(const float4*)(bp0 + 4);
                b10 = *(const float4*)bp1; b11 = *(const float4*)(bp1 + 4);
            }
        }
        // 3 passes: 16 independent MFMAs between reuses of each acc
#pragma unroll
        for (int j = 0; j < 4; ++j)
#pragma unroll
            for (int i = 0; i < 4; ++i)
                acc[i][j] = __builtin_amdgcn_mfma_f32_16x16x32_bf16(fah[i], fbh[j], acc[i][j], 0, 0, 0);
#pragma unroll
        for (int j = 0; j < 4; ++j)
#pragma unroll
            for (int i = 0; i < 4; ++i)
                acc[i][j] = __builtin_amdgcn_mfma_f32_16x16x32_bf16(fal[i], fbh[j], acc[i][j], 0, 0, 0);
#pragma unroll
        for (int j = 0; j < 4; ++j)
#pragma unroll
            for (int i = 0; i < 4; ++i)
                acc[i][j] = __builtin_amdgcn_mfma_f32_16x16x32_bf16(fah[i], fbl[j], acc[i][j], 0, 0, 0);
        __syncthreads();
    }

    // fused norms: each row's 4 chunk-threads are lanes tid^1, tid^2
    sa  += __shfl_xor(sa, 1, 64);  sa  += __shfl_xor(sa, 2, 64);
    sb0 += __shfl_xor(sb0, 1, 64); sb0 += __shfl_xor(sb0, 2, 64);
    sb1 += __shfl_xor(sb1, 1, 64); sb1 += __shfl_xor(sb1, 2, 64);
    if (c == 0) {
        vns_s[rA]  = sqrtf(sa);
        tns_s[rB0] = sqrtf(sb0);
        tns_s[rB1] = sqrtf(sb1);
    }
    if (tid < 128) rowm[tid] = 0u;
    if (tid >= 128 && tid < 384) colm[tid - 128] = 0u;
    __syncthreads();

    // epilogue: cosine + row/col max.  C layout: col = lane&15 (N), row = g*4+reg (M)
    float vr[16], tc[4];
#pragma unroll
    for (int i = 0; i < 4; ++i)
#pragma unroll
        for (int r = 0; r < 4; ++r) vr[i * 4 + r] = vns_s[wm + i * 16 + g * 4 + r];
#pragma unroll
    for (int j = 0; j < 4; ++j) tc[j] = tns_s[wn + j * 16 + fr];

    float rmx[16], cmx[4];
#pragma unroll
    for (int i = 0; i < 16; ++i) rmx[i] = -INFINITY;
#pragma unroll
    for (int j = 0; j < 4; ++j) cmx[j] = -INFINITY;
#pragma unroll
    for (int i = 0; i < 4; ++i)
#pragma unroll
        for (int j = 0; j < 4; ++j)
#pragma unroll
            for (int r = 0; r < 4; ++r) {
                float s = acc[i][j][r] / fmaxf(vr[i * 4 + r] * tc[j], EPSF);
                rmx[i * 4 + r] = fmaxf(rmx[i * 4 + r], s);
                cmx[j]         = fmaxf(cmx[j], s);
            }
#pragma unroll
    for (int off = 1; off < 16; off <<= 1)
#pragma unroll
        for (int i = 0; i < 16; ++i) rmx[i] = fmaxf(rmx[i], __shfl_xor(rmx[i], off, 64));
#pragma unroll
    for (int off = 16; off < 64; off <<= 1)
#pragma unroll
        for (int j = 0; j < 4; ++j) cmx[j] = fmaxf(cmx[j], __shfl_xor(cmx[j], off, 64));
    if (fr == 0) {
#pragma unroll
        for (int i = 0; i < 4; ++i)
#pragma unroll
            for (int r = 0; r < 4; ++r)
                atomicMax(&rowm[wm + i * 16 + g * 4 + r], fkey(rmx[i * 4 + r]));
    }
    if (g == 0) {
#pragma unroll
        for (int j = 0; j < 4; ++j) atomicMax(&colm[wn + j * 16 + fr], fkey(cmx[j]));
    }
    __syncthreads();

    // publish partials (agent scope), then last-arriver runs select; no waiting
    if (tid < 128)      ast(&rowp[(b * 2 + nt) * VL + m0 + tid], rowm[tid]);
    else if (tid < 384) ast(&colp[(b * 2 + mt) * TL + n0 + (tid - 128)], colm[tid - 128]);
    __threadfence();
    __syncthreads();
    if (tid == 0) {
        unsigned old = __hip_atomic_fetch_add(&cnt[b], 1u, __ATOMIC_ACQ_REL, __HIP_MEMORY_SCOPE_AGENT);
        sh_last = (old == 3u);
    }
    __syncthreads();
    if (!sh_last) return;

    // ---- inline ballot select (only the 4th-arriving block per batch) ----
    int lane = l, wv = wid;
    if (tid < VL) rk[tid] = max(ald(&rowp[(b * 2 + 0) * VL + tid]), ald(&rowp[(b * 2 + 1) * VL + tid]));
    ck[tid] = max(ald(&colp[(b * 2 + 0) * TL + tid]), ald(&colp[(b * 2 + 1) * TL + tid]));
    for (int i = tid; i < 768; i += 512) ast(&srcidx[b * 768 + i], 0xFFFFFFFFu);
    __syncthreads();

    int flagv = 0;
    if (tid < VL) {
        unsigned me = rk[tid];
        int cnt2 = 0;
        for (int jb = 0; jb < VL / 4; ++jb) {
            uint4 k4 = *(const uint4*)&rk[jb * 4];
            cnt2 += (k4.x > me) + (k4.y > me) + (k4.z > me) + (k4.w > me);
            cnt2 += (k4.x == me && (jb * 4 + 0) < tid) + (k4.y == me && (jb * 4 + 1) < tid)
                  + (k4.z == me && (jb * 4 + 2) < tid) + (k4.w == me && (jb * 4 + 3) < tid);
        }
        flagv = (cnt2 < KV) ? 1 : 0;
    }
    int flagt;
    {
        unsigned me = ck[tid];
        int cnt2 = 0;
        for (int jb = 0; jb < TL / 4; ++jb) {
            uint4 k4 = *(const uint4*)&ck[jb * 4];
            cnt2 += (k4.x > me) + (k4.y > me) + (k4.z > me) + (k4.w > me);
            cnt2 += (k4.x == me && (jb * 4 + 0) < tid) + (k4.y == me && (jb * 4 + 1) < tid)
                  + (k4.z == me && (jb * 4 + 2) < tid) + (k4.w == me && (jb * 4 + 3) < tid);
        }
        flagt = (cnt2 < KT) ? 1 : 0;
    }

    unsigned long long mv = __ballot(flagv);
    unsigned long long mtk = __ballot(flagt);
    if (lane == 0) {
        if (wv < 4) wsumv[wv] = __popcll(mv);
        wsumt[wv] = __popcll(mtk);
    }
    __syncthreads();

    unsigned long long ltmask = (1ull << lane) - 1ull;
    if (tid < VL) {
        int base = 0;
#pragma unroll
        for (int w2 = 0; w2 < 4; ++w2) base += (w2 < wv) ? wsumv[w2] : 0;
        int mV = wsumv[0] + wsumv[1] + wsumv[2] + wsumv[3];
        int ps = base + __popcll(mv & ltmask);
        int pu = tid - ps;
        if (flagv) ast(&srcidx[b * 768 + ps], (unsigned)tid);
        else {
            int pos = pu - (KV - mV);
            if (pos >= 0 && pos < VL - KV) ast(&srcidx[b * 768 + 382 + pos], (unsigned)tid);
        }
    }
    {
        int base = 0;
#pragma unroll
        for (int w2 = 0; w2 < 8; ++w2) base += (w2 < wv) ? wsumt[w2] : 0;
        int mT = 0;
#pragma unroll
        for (int w2 = 0; w2 < 8; ++w2) mT += wsumt[w2];
        int ps = base + __popcll(mtk & ltmask);
        int pu = tid - ps;
        if (flagt) ast(&srcidx[b * 768 + 127 + ps], (unsigned)tid);
        else {
            int pos = pu - (KT - mT);
            if (pos >= 0 && pos < TL - KT) ast(&srcidx[b * 768 + 511 + pos], (unsigned)tid);
        }
    }
}

// 256 blocks (same XCD mapping as simmax), 8 waves; each wave copies 24 rows with
// batch-prefetched srcidx (shfl broadcast); nontemporal stores
__global__ __launch_bounds__(512) void k_gather(const float* __restrict__ video,
                                                const float* __restrict__ text,
                                                const int* __restrict__ srcidx,
                                                float* __restrict__ out) {
    int bb = blockIdx.x;
    int z = bb & 7, w = bb >> 3;
    int b = z * 8 + (w >> 2);
    int q = w & 3;
    int tid = threadIdx.x;
    int l = tid & 63, wid = tid >> 6;
    const float* Vb = video + (size_t)b * VL * HD;
    const float* Tb = text  + (size_t)b * TL * HD;
    const size_t S0 = (size_t)B_ * KV, S1 = S0 + (size_t)B_ * KT, S2 = S1 + (size_t)B_ * (VL - KV);

    int base = q * 192 + wid * 24;
    int my = -1;
    if (l < 24) my = srcidx[b * 768 + base + l];

    for (int it = 0; it < 24; ++it) {
        int li = base + it;                         // 0..767 within batch
        int srow = __shfl(my, it, 64);
        size_t orow;
        const float* tens;
        if (li < 127)      { orow = (size_t)b * KV + li;               tens = Vb; }
        else if (li < 382) { orow = S0 + (size_t)b * KT + (li - 127);  tens = Tb; }
        else if (li < 511) { orow = S1 + (size_t)b * (VL - KV) + (li - 382); tens = Vb; }
        else               { orow = S2 + (size_t)b * (TL - KT) + (li - 511); tens = Tb; }
        float* op = out + orow * HD;
        if (srow >= 0) {
            const float* sp = tens + (size_t)srow * HD;
#pragma unroll
            for (int h = 0; h < 2; ++h) {
                f32x4 v = *(const f32x4*)(sp + l * 4 + h * 256);
                __builtin_nontemporal_store(v, (f32x4*)(op + l * 4 + h * 256));
            }
        } else {
            f32x4 zv = {0.f, 0.f, 0.f, 0.f};
#pragma unroll
            for (int h = 0; h < 2; ++h)
                __builtin_nontemporal_store(zv, (f32x4*)(op + l * 4 + h * 256));
        }
    }
}

extern "C" void kernel_launch(void* const* d_in, const int* in_sizes, int n_in,
                              void* d_out, int out_size, void* d_ws, size_t ws_size,
                              hipStream_t stream) {
    const float* video = (const float*)d_in[0];
    const float* text  = (const float*)d_in[1];
    unsigned* ws     = (unsigned*)d_ws;
    unsigned* cnt    = ws + WS_CNT;
    unsigned* rowp   = ws + WS_ROWP;
    unsigned* colp   = ws + WS_COLP;
    unsigned* srcidx = ws + WS_SRC;
    float*    out    = (float*)d_out;

    hipMemsetAsync(cnt, 0, B_ * sizeof(unsigned), stream);
    k_simmax<<<256, 512, 0, stream>>>(video, text, cnt, rowp, colp, srcidx);
    k_gather<<<256, 512, 0, stream>>>(video, text, (const int*)srcidx, out);
}

// Round 16
// 84.888 us; speedup vs baseline: 1.4219x; 1.4219x over previous
//
#include <hip/hip_runtime.h>
#include <math.h>

#define B_  64
#define VL 256
#define TL 512
#define HD 512
#define KV 127   // (VL-1)/2
#define KT 255   // (TL-1)/2
#define EPSF 1e-8f

typedef __attribute__((ext_vector_type(8))) short short8;
typedef __attribute__((ext_vector_type(4))) float f32x4;

// workspace layout in 4-byte elements (no init needed: every slot written each call)
#define WS_ROWP  0                       // B_*2*VL u32 partial row maxes (per n-tile)
#define WS_COLP  (B_*2*VL)               // B_*2*TL u32 partial col maxes (per m-tile)

__device__ __forceinline__ unsigned fkey(float f) {
    unsigned u = __float_as_uint(f);
    return (u & 0x80000000u) ? ~u : (u | 0x80000000u);  // order-preserving float->uint
}

__device__ __forceinline__ unsigned cvt_pk_bf16(float a, float b) {
    unsigned r;
    asm("v_cvt_pk_bf16_f32 %0, %1, %2" : "=v"(r) : "v"(a), "v"(b));
    return r;   // {bf16(a) lo, bf16(b) hi}, RNE
}

// trunc-split one pair: hh = {a.hi16,b.hi16}, ll = {bf16(a-ah), bf16(b-bh)}
__device__ __forceinline__ void split_pair(float a, float b, unsigned& hh, unsigned& ll, float& ss) {
    ss = fmaf(a, a, ss);
    ss = fmaf(b, b, ss);
    unsigned ua = __float_as_uint(a) & 0xFFFF0000u;
    unsigned ub = __float_as_uint(b) & 0xFFFF0000u;
    hh = __builtin_amdgcn_perm(ub, ua, 0x07060302u);
    ll = cvt_pk_bf16(a - __uint_as_float(ua), b - __uint_as_float(ub));
}

// stage 8 f32 -> h/l planes (uint4 each)
__device__ __forceinline__ void cvt_store8(unsigned* __restrict__ ph, unsigned* __restrict__ pl,
                                           float4 x0, float4 x1, float& ss) {
    unsigned hh0, hh1, hh2, hh3, ll0, ll1, ll2, ll3;
    split_pair(x0.x, x0.y, hh0, ll0, ss);
    split_pair(x0.z, x0.w, hh1, ll1, ss);
    split_pair(x1.x, x1.y, hh2, ll2, ss);
    split_pair(x1.z, x1.w, hh3, ll3, ss);
    *(uint4*)ph = (uint4){hh0, hh1, hh2, hh3};
    *(uint4*)pl = (uint4){ll0, ll1, ll2, ll3};
}

// per-batch 128x256 tile, K=512, 8 waves of 64x64: split-bf16 3-pass MFMA,
// dbuf LDS (A 32KB + B 64KB), chunk-XOR swizzle, plain stores, NO fences (r14 exact)
__global__ __launch_bounds__(512, 2) void k_simmax(const float* __restrict__ video,
                                                   const float* __restrict__ text,
                                                   unsigned* __restrict__ rowp,
                                                   unsigned* __restrict__ colp) {
    __shared__ __align__(16) unsigned pA[2][2][2048];   // [buf][h/l][128 rows x 16 uints]
    __shared__ __align__(16) unsigned pB[2][2][4096];   // [buf][h/l][256 rows x 16 uints]
    __shared__ float vns_s[128], tns_s[256];
    __shared__ unsigned rowm[128], colm[256];

    int bb = blockIdx.x;
    // XCD grouping: a batch's 4 blocks share one XCD (hw xcd = blockIdx % 8)
    int z = bb & 7, w = bb >> 3;
    int b  = z * 8 + (w >> 2);
    int mt = (w >> 1) & 1, nt = w & 1;
    int m0 = mt * 128, n0 = nt * 256;

    const float* Vb = video + (size_t)b * VL * HD;
    const float* Tb = text  + (size_t)b * TL * HD;

    int tid = threadIdx.x;
    int l = tid & 63, wid = tid >> 6;
    int fr = l & 15, g = l >> 4;
    int wm = (wid >> 2) * 64, wn = (wid & 3) * 64;   // wave tile: 64 x 64

    // staging: thread handles one 8-float chunk of A and two of B
    int rA = tid >> 2, c = tid & 3;
    int rB0 = rA, rB1 = 128 + rA;
    unsigned wA  = rA  * 16 + (c ^ ((rA  >> 1) & 3)) * 4;
    unsigned wB0 = rB0 * 16 + (c ^ ((rB0 >> 1) & 3)) * 4;
    unsigned wB1 = rB1 * 16 + (c ^ ((rB1 >> 1) & 3)) * 4;
    const float* aptr  = Vb + (size_t)(m0 + rA)  * HD + c * 8;
    const float* bptr0 = Tb + (size_t)(n0 + rB0) * HD + c * 8;
    const float* bptr1 = Tb + (size_t)(n0 + rB1) * HD + c * 8;

    f32x4 acc[4][4];
#pragma unroll
    for (int i = 0; i < 4; ++i)
#pragma unroll
        for (int j = 0; j < 4; ++j) acc[i][j] = (f32x4){0.f, 0.f, 0.f, 0.f};

    float sa = 0.f, sb0 = 0.f, sb1 = 0.f;

    // prologue: stage step 0; prefetch step 1 raw
    float4 a0  = *(const float4*)(aptr),      a1  = *(const float4*)(aptr + 4);
    float4 b00 = *(const float4*)(bptr0),     b01 = *(const float4*)(bptr0 + 4);
    float4 b10 = *(const float4*)(bptr1),     b11 = *(const float4*)(bptr1 + 4);
    cvt_store8(&pA[0][0][wA],  &pA[0][1][wA],  a0,  a1,  sa);
    cvt_store8(&pB[0][0][wB0], &pB[0][1][wB0], b00, b01, sb0);
    cvt_store8(&pB[0][0][wB1], &pB[0][1][wB1], b10, b11, sb1);
    a0  = *(const float4*)(aptr + 32);  a1  = *(const float4*)(aptr + 36);
    b00 = *(const float4*)(bptr0 + 32); b01 = *(const float4*)(bptr0 + 36);
    b10 = *(const float4*)(bptr1 + 32); b11 = *(const float4*)(bptr1 + 36);
    __syncthreads();

    for (int t = 0; t < 16; ++t) {
        int cur = t & 1, nxt = cur ^ 1;
        short8 fah[4], fal[4], fbh[4], fbl[4];
#pragma unroll
        for (int i = 0; i < 4; ++i) {
            int row = wm + i * 16 + fr;
            unsigned ridx = row * 16 + (g ^ ((row >> 1) & 3)) * 4;
            fah[i] = *(const short8*)&pA[cur][0][ridx];
            fal[i] = *(const short8*)&pA[cur][1][ridx];
        }
#pragma unroll
        for (int j = 0; j < 4; ++j) {
            int row = wn + j * 16 + fr;
            unsigned ridx = row * 16 + (g ^ ((row >> 1) & 3)) * 4;
            fbh[j] = *(const short8*)&pB[cur][0][ridx];
            fbl[j] = *(const short8*)&pB[cur][1][ridx];
        }
        if (t < 15) {
            cvt_store8(&pA[nxt][0][wA],  &pA[nxt][1][wA],  a0,  a1,  sa);
            cvt_store8(&pB[nxt][0][wB0], &pB[nxt][1][wB0], b00, b01, sb0);
            cvt_store8(&pB[nxt][0][wB1], &pB[nxt][1][wB1], b10, b11, sb1);
            if (t < 14) {
                const float* ap  = aptr  + (t + 2) * 32;
                const float* bp0 = bptr0 + (t + 2) * 32;
                const float* bp1 = bptr1 + (t + 2) * 32;
                a0  = *(const float4*)ap;  a1  = *(const float4*)(ap + 4);
                b00 = *(const float4*)bp0; b01 = *(const float4*)(bp0 + 4);
                b10 = *(const float4*)bp1; b11 = *(const float4*)(bp1 + 4);
            }
        }
        // 3 passes: 16 independent MFMAs between reuses of each acc
#pragma unroll
        for (int j = 0; j < 4; ++j)
#pragma unroll
            for (int i = 0; i < 4; ++i)
                acc[i][j] = __builtin_amdgcn_mfma_f32_16x16x32_bf16(fah[i], fbh[j], acc[i][j], 0, 0, 0);
#pragma unroll
        for (int j = 0; j < 4; ++j)
#pragma unroll
            for (int i = 0; i < 4; ++i)
                acc[i][j] = __builtin_amdgcn_mfma_f32_16x16x32_bf16(fal[i], fbh[j], acc[i][j], 0, 0, 0);
#pragma unroll
        for (int j = 0; j < 4; ++j)
#pragma unroll
            for (int i = 0; i < 4; ++i)
                acc[i][j] = __builtin_amdgcn_mfma_f32_16x16x32_bf16(fah[i], fbl[j], acc[i][j], 0, 0, 0);
        __syncthreads();
    }

    // fused norms: each row's 4 chunk-threads are lanes tid^1, tid^2
    sa  += __shfl_xor(sa, 1, 64);  sa  += __shfl_xor(sa, 2, 64);
    sb0 += __shfl_xor(sb0, 1, 64); sb0 += __shfl_xor(sb0, 2, 64);
    sb1 += __shfl_xor(sb1, 1, 64); sb1 += __shfl_xor(sb1, 2, 64);
    if (c == 0) {
        vns_s[rA]  = sqrtf(sa);
        tns_s[rB0] = sqrtf(sb0);
        tns_s[rB1] = sqrtf(sb1);
    }
    if (tid < 128) rowm[tid] = 0u;
    if (tid >= 128 && tid < 384) colm[tid - 128] = 0u;
    __syncthreads();

    // epilogue: cosine + row/col max.  C layout: col = lane&15 (N), row = g*4+reg (M)
    float vr[16], tc[4];
#pragma unroll
    for (int i = 0; i < 4; ++i)
#pragma unroll
        for (int r = 0; r < 4; ++r) vr[i * 4 + r] = vns_s[wm + i * 16 + g * 4 + r];
#pragma unroll
    for (int j = 0; j < 4; ++j) tc[j] = tns_s[wn + j * 16 + fr];

    float rmx[16], cmx[4];
#pragma unroll
    for (int i = 0; i < 16; ++i) rmx[i] = -INFINITY;
#pragma unroll
    for (int j = 0; j < 4; ++j) cmx[j] = -INFINITY;
#pragma unroll
    for (int i = 0; i < 4; ++i)
#pragma unroll
        for (int j = 0; j < 4; ++j)
#pragma unroll
            for (int r = 0; r < 4; ++r) {
                float s = acc[i][j][r] / fmaxf(vr[i * 4 + r] * tc[j], EPSF);
                rmx[i * 4 + r] = fmaxf(rmx[i * 4 + r], s);
                cmx[j]         = fmaxf(cmx[j], s);
            }
#pragma unroll
    for (int off = 1; off < 16; off <<= 1)
#pragma unroll
        for (int i = 0; i < 16; ++i) rmx[i] = fmaxf(rmx[i], __shfl_xor(rmx[i], off, 64));
#pragma unroll
    for (int off = 16; off < 64; off <<= 1)
#pragma unroll
        for (int j = 0; j < 4; ++j) cmx[j] = fmaxf(cmx[j], __shfl_xor(cmx[j], off, 64));
    if (fr == 0) {
#pragma unroll
        for (int i = 0; i < 4; ++i)
#pragma unroll
            for (int r = 0; r < 4; ++r)
                atomicMax(&rowm[wm + i * 16 + g * 4 + r], fkey(rmx[i * 4 + r]));
    }
    if (g == 0) {
#pragma unroll
        for (int j = 0; j < 4; ++j) atomicMax(&colm[wn + j * 16 + fr], fkey(cmx[j]));
    }
    __syncthreads();
    if (tid < 128)      rowp[(b * 2 + nt) * VL + m0 + tid] = rowm[tid];
    else if (tid < 384) colp[(b * 2 + mt) * TL + n0 + (tid - 128)] = colm[tid - 128];
}

// 256 blocks (same XCD mapping as simmax). Head: redundant per-block ballot-select
// (pure function of rowp/colp -> identical srcidx in LDS; kernel-boundary visibility,
// NO fences). Body: wave-batched gather, 24 rows/wave, nt stores.
__global__ __launch_bounds__(512) void k_gatsel(const float* __restrict__ video,
                                                const float* __restrict__ text,
                                                const unsigned* __restrict__ rowp,
                                                const unsigned* __restrict__ colp,
                                                float* __restrict__ out) {
    __shared__ __align__(16) unsigned rk[VL];
    __shared__ __align__(16) unsigned ck[TL];
    __shared__ int s_src[768];
    __shared__ int wsumv[4], wsumt[8];

    int bb = blockIdx.x;
    int z = bb & 7, w = bb >> 3;
    int b = z * 8 + (w >> 2);
    int q = w & 3;
    int tid = threadIdx.x;
    int l = tid & 63, wid = tid >> 6;

    // ---- select head (identical in all 4 blocks of batch b) ----
    if (tid < VL) rk[tid] = max(rowp[(b * 2 + 0) * VL + tid], rowp[(b * 2 + 1) * VL + tid]);
    ck[tid] = max(colp[(b * 2 + 0) * TL + tid], colp[(b * 2 + 1) * TL + tid]);
    for (int i = tid; i < 768; i += 512) s_src[i] = -1;
    __syncthreads();

    int flagv = 0;
    if (tid < VL) {
        unsigned me = rk[tid];
        int cnt = 0;
        for (int jb = 0; jb < VL / 4; ++jb) {
            uint4 k4 = *(const uint4*)&rk[jb * 4];
            cnt += (k4.x > me) + (k4.y > me) + (k4.z > me) + (k4.w > me);
            cnt += (k4.x == me && (jb * 4 + 0) < tid) + (k4.y == me && (jb * 4 + 1) < tid)
                 + (k4.z == me && (jb * 4 + 2) < tid) + (k4.w == me && (jb * 4 + 3) < tid);
        }
        flagv = (cnt < KV) ? 1 : 0;
    }
    int flagt;
    {
        unsigned me = ck[tid];
        int cnt = 0;
        for (int jb = 0; jb < TL / 4; ++jb) {
            uint4 k4 = *(const uint4*)&ck[jb * 4];
            cnt += (k4.x > me) + (k4.y > me) + (k4.z > me) + (k4.w > me);
            cnt += (k4.x == me && (jb * 4 + 0) < tid) + (k4.y == me && (jb * 4 + 1) < tid)
                 + (k4.z == me && (jb * 4 + 2) < tid) + (k4.w == me && (jb * 4 + 3) < tid);
        }
        flagt = (cnt < KT) ? 1 : 0;
    }

    unsigned long long mv = __ballot(flagv);
    unsigned long long mtk = __ballot(flagt);
    if (l == 0) {
        if (wid < 4) wsumv[wid] = __popcll(mv);
        wsumt[wid] = __popcll(mtk);
    }
    __syncthreads();

    unsigned long long ltmask = (1ull << l) - 1ull;
    if (tid < VL) {
        int base = 0;
#pragma unroll
        for (int w2 = 0; w2 < 4; ++w2) base += (w2 < wid) ? wsumv[w2] : 0;
        int mV = wsumv[0] + wsumv[1] + wsumv[2] + wsumv[3];
        int ps = base + __popcll(mv & ltmask);
        int pu = tid - ps;
        if (flagv) s_src[ps] = tid;                                    // v_mut
        else {
            int pos = pu - (KV - mV);                                  // skip first (KV-mV) unselected
            if (pos >= 0 && pos < VL - KV) s_src[382 + pos] = tid;     // v_only
        }
    }
    {
        int base = 0;
#pragma unroll
        for (int w2 = 0; w2 < 8; ++w2) base += (w2 < wid) ? wsumt[w2] : 0;
        int mT = 0;
#pragma unroll
        for (int w2 = 0; w2 < 8; ++w2) mT += wsumt[w2];
        int ps = base + __popcll(mtk & ltmask);
        int pu = tid - ps;
        if (flagt) s_src[127 + ps] = tid;                              // t_mut
        else {
            int pos = pu - (KT - mT);
            if (pos >= 0 && pos < TL - KT) s_src[511 + pos] = tid;     // t_only
        }
    }
    __syncthreads();

    // ---- gather body: this block handles quarter q (192 rows), 24 per wave ----
    const float* Vb = video + (size_t)b * VL * HD;
    const float* Tb = text  + (size_t)b * TL * HD;
    const size_t S0 = (size_t)B_ * KV, S1 = S0 + (size_t)B_ * KT, S2 = S1 + (size_t)B_ * (VL - KV);

    int base = q * 192 + wid * 24;
    int my = -1;
    if (l < 24) my = s_src[base + l];

    for (int it = 0; it < 24; ++it) {
        int li = base + it;                         // 0..767 within batch
        int srow = __shfl(my, it, 64);
        size_t orow;
        const float* tens;
        if (li < 127)      { orow = (size_t)b * KV + li;               tens = Vb; }
        else if (li < 382) { orow = S0 + (size_t)b * KT + (li - 127);  tens = Tb; }
        else if (li < 511) { orow = S1 + (size_t)b * (VL - KV) + (li - 382); tens = Vb; }
        else               { orow = S2 + (size_t)b * (TL - KT) + (li - 511); tens = Tb; }
        float* op = out + orow * HD;
        if (srow >= 0) {
            const float* sp = tens + (size_t)srow * HD;
#pragma unroll
            for (int h = 0; h < 2; ++h) {
                f32x4 v = *(const f32x4*)(sp + l * 4 + h * 256);
                __builtin_nontemporal_store(v, (f32x4*)(op + l * 4 + h * 256));
            }
        } else {
            f32x4 zv = {0.f, 0.f, 0.f, 0.f};
#pragma unroll
            for (int h = 0; h < 2; ++h)
                __builtin_nontemporal_store(zv, (f32x4*)(op + l * 4 + h * 256));
        }
    }
}

extern "C" void kernel_launch(void* const* d_in, const int* in_sizes, int n_in,
                              void* d_out, int out_size, void* d_ws, size_t ws_size,
                              hipStream_t stream) {
    const float* video = (const float*)d_in[0];
    const float* text  = (const float*)d_in[1];
    unsigned* ws   = (unsigned*)d_ws;
    unsigned* rowp = ws + WS_ROWP;
    unsigned* colp = ws + WS_COLP;
    float*    out  = (float*)d_out;

    k_simmax<<<256, 512, 0, stream>>>(video, text, rowp, colp);
    k_gatsel<<<256, 512, 0, stream>>>(video, text, rowp, colp, out);
}